// Round 6
// baseline (223.131 us; speedup 1.0000x reference)
//
#include <hip/hip_runtime.h>
#include <hip/hip_cooperative_groups.h>
#include <math.h>

namespace cg = cooperative_groups;

namespace {

constexpr int Bn = 8;
constexpr int Hn = 256;
constexpr int Wn = 256;
constexpr int HW = Hn * Wn;       // 65536
constexpr int Ntot = Bn * HW;     // 524288
constexpr int GRID = 512;         // 8 batches x 64 groups; 2 blocks/CU resident
constexpr float INF_F = 131138.0f; // sum(n*n for n in shape)+1
constexpr float EPSv = 1e-6f;

// 256-thread block sum; returns full sum to all threads. Fixed order -> deterministic.
__device__ __forceinline__ float blkred(float v, float* sm) {
    #pragma unroll
    for (int o = 32; o > 0; o >>= 1) v += __shfl_down(v, o, 64);
    int lane = threadIdx.x & 63, wid = threadIdx.x >> 6;
    __syncthreads();
    if (lane == 0) sm[wid] = v;
    __syncthreads();
    return sm[0] + sm[1] + sm[2] + sm[3];
}

__device__ __forceinline__ float getc(const float4& v, int r) {
    return r == 0 ? v.x : r == 1 ? v.y : r == 2 ? v.z : v.w;
}

// Wave-cooperative exact 1D DT over a 256-line staged in LDS as
// u[j] = f[j] + j^2:  res(i) = i^2 + min_j (u[j] + (-2i)*j).
// All intermediates exact integers (|.| < 2^24) -> bit-identical to the
// reference's brute-force (i-j)^2 + f[j]. Lane l computes i in {4l..4l+3}.
// Per-lane fma constant (-2i) + incremental float j => 28 wave-instr per q.
__device__ __forceinline__ void dt_wave4(const float* __restrict__ u,
                                         int lane, float res[4]) {
    const float4* u4 = reinterpret_cast<const float4*>(u);
    float fi[4], ni2[4], mA[4], mB[4];
    #pragma unroll
    for (int r = 0; r < 4; ++r) {
        fi[r]  = (float)(4 * lane + r);
        ni2[r] = -2.0f * fi[r];
        mA[r] = 3.0e38f; mB[r] = 3.0e38f;
    }
    float jb = 0.f;
    #pragma unroll 8
    for (int q = 0; q < 64; ++q) {
        float4 uu = u4[q];             // wave-uniform broadcast read
        float j0 = jb, j1 = jb + 1.f, j2 = jb + 2.f, j3 = jb + 3.f;
        jb += 4.f;
        #pragma unroll
        for (int r = 0; r < 4; ++r) {
            mA[r] = fminf(fminf(mA[r], fmaf(ni2[r], j0, uu.x)),
                          fmaf(ni2[r], j1, uu.y));   // -> v_min3_f32
            mB[r] = fminf(fminf(mB[r], fmaf(ni2[r], j2, uu.z)),
                          fmaf(ni2[r], j3, uu.w));
        }
    }
    #pragma unroll
    for (int r = 0; r < 4; ++r)
        res[r] = fminf(mA[r], mB[r]) + fi[r] * fi[r];
}

// One cooperative kernel, three stages separated by grid.sync().
// Stage AW: block (b, h0): elementwise partials + B-DT + W-DT on 4 rows,
//           transpose-write gT[b][w][h] and sqT[b][w][h] (float4 scatters).
// Stage H : block (b, w0): contiguous H-DT + fused sqrt*(1-p)^2 + reduce.
// Stage F : block 0 combines.
__global__ __launch_bounds__(256, 2) void fused(const float* __restrict__ lg,
                                                const float* __restrict__ tg,
                                                float* __restrict__ gT,
                                                float* __restrict__ sqT,
                                                float* __restrict__ pa,
                                                float* __restrict__ bp,
                                                float* __restrict__ out) {
    cg::grid_group grid = cg::this_grid();
    __shared__ __align__(16) float uL[4][Wn];   // DT input line per wave
    __shared__ __align__(16) float vL[4][Wn];   // W-DT results (for transpose)
    __shared__ __align__(16) float sL[4][Wn];   // (1-p)^2     (for transpose)
    __shared__ float sm[4];
    int tid = threadIdx.x, wv = tid >> 6, lane = tid & 63;
    int blk = blockIdx.x;
    int b  = blk >> 6;
    int h0 = (blk & 63) * 4;
    int h  = h0 + wv;                 // this wave's row
    int w4 = lane * 4;

    // ---------------- Stage AW ----------------
    float4 xg = *reinterpret_cast<const float4*>(lg + (size_t)b * HW + h * Wn + w4);
    float4 tgv[Bn];
    #pragma unroll
    for (int j = 0; j < Bn; ++j)
        tgv[j] = *reinterpret_cast<const float4*>(tg + (size_t)j * HW + h * Wn + w4);
    float d2[Bn];
    #pragma unroll
    for (int j = 0; j < Bn; ++j) { int e = b - j; d2[j] = (float)(e * e); }

    float sp = 0.f, st = 0.f, spt = 0.f, fo = 0.f;
    float uv[4], sqv[4];
    #pragma unroll
    for (int r = 0; r < 4; ++r) {
        float x  = getc(xg, r);
        float tv = getc(tgv[b], r);
        float p  = 1.f / (1.f + expf(-x));
        sp  += p;
        st  += tv;
        spt += p * tv;
        float ce = fmaxf(x, 0.f) - x * tv + log1pf(expf(-fabsf(x)));
        float pt = p * tv + (1.f - p) * (1.f - tv);
        float om = 1.f - pt;
        fo += 0.25f * om * om * ce;          // ALPHA=0.25, GAMMA=2
        float qn = 1.f - p;
        sqv[r] = qn * qn;
        // axis-B DT at this (b) output plane: min over all 8 masks (exact)
        float m = 3.0e38f;
        #pragma unroll
        for (int j = 0; j < Bn; ++j) {
            float fv = getc(tgv[j], r) > 0.5f ? INF_F : 0.f;
            m = fminf(m, fv + d2[j]);
        }
        float wF = (float)(w4 + r);
        uv[r] = m + wF * wF;                 // stage u = f + w^2 for W-DT
    }
    *reinterpret_cast<float4*>(&uL[wv][w4]) = make_float4(uv[0], uv[1], uv[2], uv[3]);
    *reinterpret_cast<float4*>(&sL[wv][w4]) = make_float4(sqv[0], sqv[1], sqv[2], sqv[3]);
    // wave-local LDS dependency: compiler inserts lgkmcnt wait
    float res[4];
    dt_wave4(uL[wv], lane, res);
    *reinterpret_cast<float4*>(&vL[wv][w4]) = make_float4(res[0], res[1], res[2], res[3]);

    sp  = blkred(sp, sm);    // contains __syncthreads -> vL/sL visible after
    st  = blkred(st, sm);
    spt = blkred(spt, sm);
    fo  = blkred(fo, sm);
    if (tid == 0) {
        float* o = pa + blk * 4;
        o[0] = sp; o[1] = st; o[2] = spt; o[3] = fo;
    }
    __syncthreads();
    // transpose-write: thread tid = w; 4 h-values -> one float4 row chunk
    {
        float4 gv = make_float4(vL[0][tid], vL[1][tid], vL[2][tid], vL[3][tid]);
        float4 sv = make_float4(sL[0][tid], sL[1][tid], sL[2][tid], sL[3][tid]);
        *reinterpret_cast<float4*>(gT  + ((size_t)b * Wn + tid) * Hn + h0) = gv;
        *reinterpret_cast<float4*>(sqT + ((size_t)b * Wn + tid) * Hn + h0) = sv;
    }
    __threadfence();
    grid.sync();

    // ---------------- Stage H ----------------
    int w = (blk & 63) * 4 + wv;      // this wave's column line
    float4 gv = *reinterpret_cast<const float4*>(gT  + ((size_t)b * Wn + w) * Hn + w4);
    float4 sv = *reinterpret_cast<const float4*>(sqT + ((size_t)b * Wn + w) * Hn + w4);
    {
        float j0 = (float)w4;
        float4 u4v = make_float4(gv.x + j0 * j0,
                                 gv.y + (j0 + 1.f) * (j0 + 1.f),
                                 gv.z + (j0 + 2.f) * (j0 + 2.f),
                                 gv.w + (j0 + 3.f) * (j0 + 3.f));
        *reinterpret_cast<float4*>(&uL[wv][w4]) = u4v;
    }
    float res2[4];
    dt_wave4(uL[wv], lane, res2);
    float acc = sqrtf(res2[0]) * sv.x + sqrtf(res2[1]) * sv.y
              + sqrtf(res2[2]) * sv.z + sqrtf(res2[3]) * sv.w;
    acc = blkred(acc, sm);
    if (tid == 0) bp[blk] = acc;
    __threadfence();
    grid.sync();

    // ---------------- Stage F ----------------
    if (blk != 0) return;
    float sp2  = pa[tid * 4 + 0] + pa[(tid + 256) * 4 + 0];
    float st2  = pa[tid * 4 + 1] + pa[(tid + 256) * 4 + 1];
    float spt2 = pa[tid * 4 + 2] + pa[(tid + 256) * 4 + 2];
    float fo2  = pa[tid * 4 + 3] + pa[(tid + 256) * 4 + 3];
    float bs   = bp[tid] + bp[tid + 256];
    sp2  = blkred(sp2, sm);
    st2  = blkred(st2, sm);
    spt2 = blkred(spt2, sm);
    fo2  = blkred(fo2, sm);
    bs   = blkred(bs, sm);
    if (tid == 0) {
        float dice = 1.f - (2.f * spt2 + EPSv) / (sp2 + st2 + EPSv);
        float boundary = bs / (float)Ntot;
        float focal = fo2 / (float)Ntot;
        out[0] = 1.0f * dice + 0.5f * boundary + 1.0f * focal;
    }
}

} // namespace

extern "C" void kernel_launch(void* const* d_in, const int* in_sizes, int n_in,
                              void* d_out, int out_size, void* d_ws, size_t ws_size,
                              hipStream_t stream) {
    const float* lg = (const float*)d_in[0];   // logits  [8,1,256,256] f32
    const float* tg = (const float*)d_in[1];   // targets [8,1,256,256] f32
    float* ws  = (float*)d_ws;
    float* gT  = ws;                       // [b][w][h] post B+W DT, 2 MB
    float* sqT = ws + Ntot;                // [b][w][h] (1-p)^2,     2 MB
    float* pa  = ws + 2 * Ntot;            // 512 blocks * 4 partials
    float* bp  = ws + 2 * Ntot + 2048;     // 512 boundary partials
    float* outp = (float*)d_out;

    void* params[] = {(void*)&lg, (void*)&tg, (void*)&gT, (void*)&sqT,
                      (void*)&pa, (void*)&bp, (void*)&outp};
    hipLaunchCooperativeKernel((const void*)fused, dim3(GRID), dim3(256),
                               params, 0, stream);
}

// Round 7
// 30.784 us; speedup vs baseline: 7.2483x; 7.2483x over previous
//
#include <hip/hip_runtime.h>
#include <math.h>

namespace {

constexpr int Bn = 8;
constexpr int Hn = 256;
constexpr int Wn = 256;
constexpr int HW = Hn * Wn;       // 65536
constexpr int Ntot = Bn * HW;     // 524288
constexpr float INF_F = 131138.0f; // sum(n*n for n in shape)+1
constexpr float EPSv = 1e-6f;

// 256-thread block sum; returns full sum to all threads. Fixed order -> deterministic.
__device__ __forceinline__ float blkred(float v, float* sm) {
    #pragma unroll
    for (int o = 32; o > 0; o >>= 1) v += __shfl_down(v, o, 64);
    int lane = threadIdx.x & 63, wid = threadIdx.x >> 6;
    __syncthreads();
    if (lane == 0) sm[wid] = v;
    __syncthreads();
    return sm[0] + sm[1] + sm[2] + sm[3];
}

// Wave-cooperative exact 1D DT over a 256-line staged in LDS as
// u[j] = f[j] + j^2:  res(i) = i^2 + min_j (u[j] + (-2i)*j).
// All intermediates exact integers (< 2^24) -> bit-identical to the
// reference's brute-force (i-j)^2 + f[j]. Lane l computes i in {4l..4l+3}:
// 64 wave-uniform broadcast ds_read_b128 per line (4x fewer than
// thread-per-i). Two min chains per output; fminf pairs fuse to v_min3_f32.
__device__ __forceinline__ void dt_wave4(const float* __restrict__ u,
                                         int lane, float res[4]) {
    const float4* u4 = reinterpret_cast<const float4*>(u);
    float fi[4], ni2[4], mA[4], mB[4];
    #pragma unroll
    for (int r = 0; r < 4; ++r) {
        fi[r]  = (float)(4 * lane + r);
        ni2[r] = -2.0f * fi[r];
        mA[r] = 3.0e38f; mB[r] = 3.0e38f;
    }
    float jb = 0.f;
    #pragma unroll 8
    for (int q = 0; q < 64; ++q) {
        float4 uu = u4[q];             // wave-uniform broadcast read
        float j0 = jb, j1 = jb + 1.f, j2 = jb + 2.f, j3 = jb + 3.f;
        jb += 4.f;
        #pragma unroll
        for (int r = 0; r < 4; ++r) {
            mA[r] = fminf(fminf(mA[r], fmaf(ni2[r], j0, uu.x)),
                          fmaf(ni2[r], j1, uu.y));   // -> v_min3_f32
            mB[r] = fminf(fminf(mB[r], fmaf(ni2[r], j2, uu.z)),
                          fmaf(ni2[r], j3, uu.w));
        }
    }
    #pragma unroll
    for (int r = 0; r < 4; ++r)
        res[r] = fminf(mA[r], mB[r]) + fi[r] * fi[r];
}

// Kernel A: per-(h,w) pixel, loop batches. Sigmoid + dice/focal partials,
// axis-B DT (n=8) in regs. (Identical to the 28.6us R2 version.)
__global__ __launch_bounds__(256) void kA(const float* __restrict__ lg,
                                          const float* __restrict__ tg,
                                          float* __restrict__ f1,
                                          float* __restrict__ pa) {
    int t = blockIdx.x * 256 + threadIdx.x;   // 0..HW-1
    float sp = 0.f, st = 0.f, spt = 0.f, fo = 0.f;
    float fv[Bn];
    #pragma unroll
    for (int b = 0; b < Bn; b++) {
        float x  = lg[b * HW + t];
        float tv = tg[b * HW + t];
        float p  = 1.f / (1.f + expf(-x));
        sp  += p;
        st  += tv;
        spt += p * tv;
        float ce = fmaxf(x, 0.f) - x * tv + log1pf(expf(-fabsf(x)));
        float pt = p * tv + (1.f - p) * (1.f - tv);
        float om = 1.f - pt;
        fo += 0.25f * om * om * ce;          // ALPHA=0.25, GAMMA=2
        fv[b] = (tv > 0.5f) ? INF_F : 0.f;
    }
    #pragma unroll
    for (int i = 0; i < Bn; i++) {
        float m = fv[0] + (float)(i * i);
        #pragma unroll
        for (int j = 1; j < Bn; j++) {
            int d = i - j;
            m = fminf(m, fv[j] + (float)(d * d));
        }
        f1[i * HW + t] = m;
    }
    __shared__ float sm[4];
    sp  = blkred(sp, sm);
    st  = blkred(st, sm);
    spt = blkred(spt, sm);
    fo  = blkred(fo, sm);
    if (threadIdx.x == 0) {
        float* o = pa + blockIdx.x * 4;
        o[0] = sp; o[1] = st; o[2] = spt; o[3] = fo;
    }
}

// Kernel W: DT along W. 4 lines/block, wave per line; float4 coalesced I/O.
__global__ __launch_bounds__(256) void kW(const float* __restrict__ f1,
                                          float* __restrict__ g) {
    __shared__ __align__(16) float u[4][Wn];
    int wv = threadIdx.x >> 6, lane = threadIdx.x & 63;
    int line = blockIdx.x * 4 + wv;        // b*Hn + h
    float4 v = reinterpret_cast<const float4*>(f1 + (size_t)line * Wn)[lane];
    float j0 = (float)(4 * lane);
    v.x += j0 * j0;
    v.y += (j0 + 1.f) * (j0 + 1.f);
    v.z += (j0 + 2.f) * (j0 + 2.f);
    v.w += (j0 + 3.f) * (j0 + 3.f);
    reinterpret_cast<float4*>(u[wv])[lane] = v;
    __syncthreads();
    float res[4];
    dt_wave4(u[wv], lane, res);
    reinterpret_cast<float4*>(g + (size_t)line * Wn)[lane] =
        make_float4(res[0], res[1], res[2], res[3]);
}

// Kernel T: per-batch 32x32 tile transpose g[b][h][w] -> gT[b][w][h].
// (Identical to the R2 version.)
__global__ __launch_bounds__(256) void kT(const float* __restrict__ g,
                                          float* __restrict__ gT) {
    int bid = blockIdx.x;          // b*64 + ty*8 + tx
    int b  = bid >> 6;
    int ty = (bid >> 3) & 7;
    int tx = bid & 7;
    __shared__ float t[32][33];
    int c  = threadIdx.x & 31;
    int r0 = threadIdx.x >> 5;     // 0..7
    const float* gb = g + (size_t)b * HW;
    #pragma unroll
    for (int k = 0; k < 4; ++k) {
        int r = r0 + 8 * k;
        t[r][c] = gb[(ty * 32 + r) * Wn + tx * 32 + c];
    }
    __syncthreads();
    float* gTb = gT + (size_t)b * HW;
    #pragma unroll
    for (int k = 0; k < 4; ++k) {
        int r = r0 + 8 * k;        // w within tile
        gTb[(tx * 32 + r) * Hn + ty * 32 + c] = t[c][r];
    }
}

// Kernel H: DT along H on transposed layout (contiguous float4), wave per
// line, fused sqrt * (1-p)^2 (lg re-read strided, L2-resident) + reduce.
__global__ __launch_bounds__(256) void kH(const float* __restrict__ gT,
                                          const float* __restrict__ lg,
                                          float* __restrict__ bp) {
    __shared__ __align__(16) float u[4][Hn];
    __shared__ float sm[4];
    int wv = threadIdx.x >> 6, lane = threadIdx.x & 63;
    int line = blockIdx.x * 4 + wv;        // b*Wn + w
    int b = line >> 8, w = line & 255;
    float4 v = reinterpret_cast<const float4*>(gT + (size_t)line * Hn)[lane];
    float j0 = (float)(4 * lane);
    v.x += j0 * j0;
    v.y += (j0 + 1.f) * (j0 + 1.f);
    v.z += (j0 + 2.f) * (j0 + 2.f);
    v.w += (j0 + 3.f) * (j0 + 3.f);
    reinterpret_cast<float4*>(u[wv])[lane] = v;
    // boundary-term logits: 4 strided scalars, issued early, L2-resident
    const float* lb = lg + (size_t)b * HW + w;
    float xv[4];
    #pragma unroll
    for (int r = 0; r < 4; ++r)
        xv[r] = lb[(size_t)(4 * lane + r) * Wn];
    __syncthreads();
    float res[4];
    dt_wave4(u[wv], lane, res);
    float acc = 0.f;
    #pragma unroll
    for (int r = 0; r < 4; ++r) {
        float s = 1.f / (1.f + expf(xv[r]));   // = 1 - sigmoid(x)
        acc += sqrtf(res[r]) * s * s;
    }
    acc = blkred(acc, sm);
    if (threadIdx.x == 0) bp[blockIdx.x] = acc;
}

// Kernel D: final combine. 256 threads, one block.
__global__ __launch_bounds__(256) void kD(const float* __restrict__ pa,
                                          const float* __restrict__ bp,
                                          float* __restrict__ out) {
    __shared__ float sm[4];
    int t = threadIdx.x;
    float sp  = pa[t * 4 + 0];
    float st  = pa[t * 4 + 1];
    float spt = pa[t * 4 + 2];
    float fo  = pa[t * 4 + 3];
    float bs  = bp[t] + bp[t + 256];
    sp  = blkred(sp, sm);
    st  = blkred(st, sm);
    spt = blkred(spt, sm);
    fo  = blkred(fo, sm);
    bs  = blkred(bs, sm);
    if (t == 0) {
        float dice = 1.f - (2.f * spt + EPSv) / (sp + st + EPSv);
        float boundary = bs / (float)Ntot;
        float focal = fo / (float)Ntot;
        out[0] = 1.0f * dice + 0.5f * boundary + 1.0f * focal;
    }
}

} // namespace

extern "C" void kernel_launch(void* const* d_in, const int* in_sizes, int n_in,
                              void* d_out, int out_size, void* d_ws, size_t ws_size,
                              hipStream_t stream) {
    const float* lg = (const float*)d_in[0];   // logits  [8,1,256,256] f32
    const float* tg = (const float*)d_in[1];   // targets [8,1,256,256] f32
    float* ws = (float*)d_ws;
    float* f1 = ws;                        // [b][h][w] post B-DT
    float* g  = ws + Ntot;                 // [b][h][w] post W-DT
    float* gT = ws + 2 * Ntot;             // [b][w][h]
    float* pa = ws + 3 * Ntot;             // 256 blocks * 4 partials
    float* bp = ws + 3 * Ntot + 1024;      // 512 boundary partials

    kA<<<HW / 256, 256, 0, stream>>>(lg, tg, f1, pa);
    kW<<<Bn * Hn / 4, 256, 0, stream>>>(f1, g);
    kT<<<Bn * 64, 256, 0, stream>>>(g, gT);
    kH<<<Bn * Wn / 4, 256, 0, stream>>>(gT, lg, bp);
    kD<<<1, 256, 0, stream>>>(pa, bp, (float*)d_out);
}

// Round 8
// 29.947 us; speedup vs baseline: 7.4508x; 1.0279x over previous
//
#include <hip/hip_runtime.h>
#include <math.h>

namespace {

constexpr int Bn = 8;
constexpr int Hn = 256;
constexpr int Wn = 256;
constexpr int HW = Hn * Wn;       // 65536
constexpr int Ntot = Bn * HW;     // 524288
constexpr float INF_F = 131138.0f; // sum(n*n for n in shape)+1
constexpr float EPSv = 1e-6f;

// 256-thread block sum; returns full sum to all threads. Fixed order -> deterministic.
__device__ __forceinline__ float blkred(float v, float* sm) {
    #pragma unroll
    for (int o = 32; o > 0; o >>= 1) v += __shfl_down(v, o, 64);
    int lane = threadIdx.x & 63, wid = threadIdx.x >> 6;
    __syncthreads();
    if (lane == 0) sm[wid] = v;
    __syncthreads();
    return sm[0] + sm[1] + sm[2] + sm[3];
}

// Thread-per-i exact 1D DT over a 256-line staged in LDS as u[j]=f[j]+j^2:
// res(i) = i^2 + min_j (u[j] + (-2i)*j). All intermediates exact integers
// (<2^24) -> bit-identical to the reference's brute force. All lanes read the
// same u4[q] -> wave-uniform broadcast ds_read_b128. Two min chains; the
// fminf pairs fuse to v_min3_f32 (6 VALU/q).
__device__ __forceinline__ float dt_thread(const float* __restrict__ u, int i) {
    const float4* u4 = reinterpret_cast<const float4*>(u);
    float ni2 = -2.0f * (float)i;
    float mA = 3.0e38f, mB = 3.0e38f;
    float jb = 0.f;
    #pragma unroll 8
    for (int q = 0; q < 64; ++q) {
        float4 uu = u4[q];
        mA = fminf(fminf(mA, fmaf(ni2, jb, uu.x)),
                   fmaf(ni2, jb + 1.f, uu.y));
        mB = fminf(fminf(mB, fmaf(ni2, jb + 2.f, uu.z)),
                   fmaf(ni2, jb + 3.f, uu.w));
        jb += 4.f;
    }
    return fminf(mA, mB) + (float)i * (float)i;
}

// Fused A+W+T: block = one (b,h) row (2048 blocks, 8/CU). Per thread (w):
// elementwise partials for own (b,h,w), axis-B DT for own b (needs all 8
// masks at (h,w); tg re-read 8x, L2/L3-resident), W-DT thread-per-i, then
// TRANSPOSED scatter store of gT (fire-and-forget; kills kT + f1/g buffers).
__global__ __launch_bounds__(256) void kAW(const float* __restrict__ lg,
                                           const float* __restrict__ tg,
                                           float* __restrict__ gT,
                                           float* __restrict__ pa) {
    int blk = blockIdx.x;            // b*Hn + h
    int b = blk >> 8, h = blk & 255;
    int w = threadIdx.x;
    int t = h * Wn + w;
    float x = lg[(size_t)b * HW + t];
    float tv = 0.f;
    float m = 3.0e38f;
    #pragma unroll
    for (int j = 0; j < Bn; ++j) {   // coalesced plane reads
        float tj = tg[(size_t)j * HW + t];
        if (j == b) tv = tj;
        float fv = (tj > 0.5f) ? INF_F : 0.f;
        int d = b - j;
        m = fminf(m, fv + (float)(d * d));
    }
    float p  = 1.f / (1.f + expf(-x));
    float sp = p, st = tv, spt = p * tv;
    float ce = fmaxf(x, 0.f) - x * tv + log1pf(expf(-fabsf(x)));
    float pt = p * tv + (1.f - p) * (1.f - tv);
    float om = 1.f - pt;
    float fo = 0.25f * om * om * ce;         // ALPHA=0.25, GAMMA=2

    __shared__ __align__(16) float u[Wn];
    __shared__ float sm[4];
    u[w] = m + (float)w * (float)w;          // u = f + w^2
    __syncthreads();
    float res = dt_thread(u, w);
    gT[((size_t)b * Wn + w) * Hn + h] = res; // transposed scatter (4B, 1KB stride)

    sp  = blkred(sp, sm);
    st  = blkred(st, sm);
    spt = blkred(spt, sm);
    fo  = blkred(fo, sm);
    if (threadIdx.x == 0) {
        float* o = pa + blk * 4;
        o[0] = sp; o[1] = st; o[2] = spt; o[3] = fo;
    }
}

// Kernel H: block = one (b,w) column line (2048 blocks). Coalesced gT reads,
// thread-per-i DT, fused sqrt * (1-p)^2 (1 strided lg scalar/thread,
// L2/L3-resident) + block reduce.
__global__ __launch_bounds__(256) void kH(const float* __restrict__ gT,
                                          const float* __restrict__ lg,
                                          float* __restrict__ bp) {
    int blk = blockIdx.x;            // b*Wn + w
    int b = blk >> 8, w = blk & 255;
    int i = threadIdx.x;             // h
    __shared__ __align__(16) float u[Hn];
    __shared__ float sm[4];
    u[i] = gT[(size_t)blk * Hn + i] + (float)i * (float)i;
    float x = lg[(size_t)b * HW + i * Wn + w];  // strided scalar, issued early
    __syncthreads();
    float res = dt_thread(u, i);
    float s = 1.f / (1.f + expf(x));            // = 1 - sigmoid(x)
    float acc = sqrtf(res) * s * s;
    acc = blkred(acc, sm);
    if (i == 0) bp[blk] = acc;
}

// Kernel D: final combine over 2048-block partials. One block.
__global__ __launch_bounds__(256) void kD(const float* __restrict__ pa,
                                          const float* __restrict__ bp,
                                          float* __restrict__ out) {
    __shared__ float sm[4];
    int t = threadIdx.x;
    float sp = 0.f, st = 0.f, spt = 0.f, fo = 0.f, bs = 0.f;
    #pragma unroll
    for (int k = 0; k < 8; ++k) {
        const float* o = pa + (size_t)(t + 256 * k) * 4;
        sp += o[0]; st += o[1]; spt += o[2]; fo += o[3];
        bs += bp[t + 256 * k];
    }
    sp  = blkred(sp, sm);
    st  = blkred(st, sm);
    spt = blkred(spt, sm);
    fo  = blkred(fo, sm);
    bs  = blkred(bs, sm);
    if (t == 0) {
        float dice = 1.f - (2.f * spt + EPSv) / (sp + st + EPSv);
        float boundary = bs / (float)Ntot;
        float focal = fo / (float)Ntot;
        out[0] = 1.0f * dice + 0.5f * boundary + 1.0f * focal;
    }
}

} // namespace

extern "C" void kernel_launch(void* const* d_in, const int* in_sizes, int n_in,
                              void* d_out, int out_size, void* d_ws, size_t ws_size,
                              hipStream_t stream) {
    const float* lg = (const float*)d_in[0];   // logits  [8,1,256,256] f32
    const float* tg = (const float*)d_in[1];   // targets [8,1,256,256] f32
    float* ws = (float*)d_ws;
    float* gT = ws;                        // [b][w][h] post B+W DT, 2 MB
    float* pa = ws + Ntot;                 // 2048 blocks * 4 partials
    float* bp = ws + Ntot + 8192;          // 2048 boundary partials

    kAW<<<Bn * Hn, 256, 0, stream>>>(lg, tg, gT, pa);
    kH<<<Bn * Wn, 256, 0, stream>>>(gT, lg, bp);
    kD<<<1, 256, 0, stream>>>(pa, bp, (float*)d_out);
}